// Round 1
// baseline (607.882 us; speedup 1.0000x reference)
//
#include <hip/hip_runtime.h>
#include <math.h>

#define ALPHA 0.2f

__device__ __forceinline__ float lrelu(float x) { return x > 0.f ? x : ALPHA * x; }
__device__ __forceinline__ float elu1(float x)  { return x > 0.f ? x : (__expf(x) - 1.f); }

// ---------------------------------------------------------------------------
// Generic f32 GEMM: C[m][j] (+z col offset) = sum_k A[m][k] * B_z[k][j]
// tile 64x64, Ktile 16, 256 threads, 4x4 micro-tile per thread.
// grid: (Ncols/64, M/64, Z)
// ---------------------------------------------------------------------------
__global__ __launch_bounds__(256) void gemm64(
    const float* __restrict__ A, const float* __restrict__ B, float* __restrict__ C,
    int K, int lda, int ldb, int ldc, long bzStride, int czColOff)
{
    __shared__ float As[64][20];   // pad to 20 floats (80B row, 16B-aligned cols)
    __shared__ float Bs[16][64];

    const int tid = threadIdx.x;
    const int tx = tid & 15, ty = tid >> 4;
    const int m0 = blockIdx.y * 64;
    const int j0 = blockIdx.x * 64;
    const int z  = blockIdx.z;

    const float* Bz = B + (long)z * bzStride;
    float*       Cz = C + (long)z * czColOff;

    const int ar = tid >> 2,  ac = (tid & 3) * 4;   // A tile load: 64 rows x 16 k
    const int br = tid >> 4,  bc = (tid & 15) * 4;  // B tile load: 16 k x 64 cols

    float acc[4][4] = {};

    for (int k0 = 0; k0 < K; k0 += 16) {
        float4 av = *(const float4*)(A  + (long)(m0 + ar) * lda + k0 + ac);
        float4 bv = *(const float4*)(Bz + (long)(k0 + br) * ldb + j0 + bc);
        __syncthreads();
        *(float4*)&As[ar][ac] = av;
        *(float4*)&Bs[br][bc] = bv;
        __syncthreads();
#pragma unroll
        for (int kk = 0; kk < 16; ++kk) {
            float a0 = As[ty * 4 + 0][kk];
            float a1 = As[ty * 4 + 1][kk];
            float a2 = As[ty * 4 + 2][kk];
            float a3 = As[ty * 4 + 3][kk];
            float4 b = *(float4*)&Bs[kk][tx * 4];
            acc[0][0] += a0 * b.x; acc[0][1] += a0 * b.y; acc[0][2] += a0 * b.z; acc[0][3] += a0 * b.w;
            acc[1][0] += a1 * b.x; acc[1][1] += a1 * b.y; acc[1][2] += a1 * b.z; acc[1][3] += a1 * b.w;
            acc[2][0] += a2 * b.x; acc[2][1] += a2 * b.y; acc[2][2] += a2 * b.z; acc[2][3] += a2 * b.w;
            acc[3][0] += a3 * b.x; acc[3][1] += a3 * b.y; acc[3][2] += a3 * b.z; acc[3][3] += a3 * b.w;
        }
    }
#pragma unroll
    for (int r = 0; r < 4; ++r) {
        float4 o = make_float4(acc[r][0], acc[r][1], acc[r][2], acc[r][3]);
        *(float4*)(Cz + (long)(m0 + ty * 4 + r) * ldc + j0 + tx * 4) = o;
    }
}

// ---------------------------------------------------------------------------
// f1/f2: one wave per (h, row). hsrc layout [row][HH][128]; a layout [h][256].
// f1[h*BN + row] = dot(hrow, a[h][0:128]); f2 = dot(hrow, a[h][128:256]).
// ---------------------------------------------------------------------------
__global__ __launch_bounds__(256) void fdot(
    const float* __restrict__ hsrc, const float* __restrict__ a,
    float* __restrict__ f1, float* __restrict__ f2, int HH, int BN)
{
    const int w = blockIdx.x * 4 + (threadIdx.x >> 6);
    const int lane = threadIdx.x & 63;
    const int h = w / BN;
    const int rn = w - h * BN;

    const float* row = hsrc + ((long)rn * HH + h) * 128;
    const float* ah = a + h * 256;

    float2 v = *(const float2*)(row + lane * 2);
    float s1 = v.x * ah[lane * 2] + v.y * ah[lane * 2 + 1];
    float s2 = v.x * ah[128 + lane * 2] + v.y * ah[128 + lane * 2 + 1];
#pragma unroll
    for (int off = 32; off; off >>= 1) {
        s1 += __shfl_down(s1, off);
        s2 += __shfl_down(s2, off);
    }
    if (lane == 0) {
        f1[h * BN + rn] = s1;
        f2[h * BN + rn] = s2;
    }
}

// ---------------------------------------------------------------------------
// f2max per (h,b): one 64-thread block per hb, scan N values.
// ---------------------------------------------------------------------------
__global__ __launch_bounds__(64) void colmax(
    const float* __restrict__ f2, float* __restrict__ f2max, int N)
{
    const int hb = blockIdx.x;
    const int lane = threadIdx.x;
    float m = -1e30f;
    for (int k = lane; k < N; k += 64) m = fmaxf(m, f2[hb * N + k]);
#pragma unroll
    for (int off = 32; off; off >>= 1) m = fmaxf(m, __shfl_down(m, off));
    if (lane == 0) f2max[hb] = m;
}

// ---------------------------------------------------------------------------
// Fused attention: out[b][i][h][f] = act( (1/l_i) * sum_j exp(lrelu(f1_i+f2_j)-m_i) * hsrc[b][j][h][f] )
// m_i = lrelu(f1_i + max_j f2_j)  (lrelu monotone -> exact softmax max).
// Block 256; i-tile = 16*IPT rows; j staged in 32-row LDS tiles.
// Thread (isl=tid/16, fg=tid&15) accumulates IPT rows x 8 features.
// ---------------------------------------------------------------------------
template <int IPT>
__global__ __launch_bounds__(256) void attn(
    const float* __restrict__ hsrc, const float* __restrict__ f1g,
    const float* __restrict__ f2g, const float* __restrict__ f2maxg,
    float* __restrict__ out, int N, int HH, int elu2)
{
    const int F = 128, JT = 32;
    const int ITILE = 16 * IPT;

    __shared__ float hlds[32][128];
    __shared__ float plds[32][64];
    __shared__ float f1l[64], ml[64];

    const int tid = threadIdx.x;
    const int hy = blockIdx.y, bz = blockIdx.z;
    const int hb = hy * gridDim.z + bz;       // h*B + b
    const int i0 = blockIdx.x * ITILE;

    const float f2m = f2maxg[hb];
    if (tid < ITILE) {
        float v = f1g[hb * N + i0 + tid];
        f1l[tid] = v;
        ml[tid] = lrelu(v + f2m);
    }

    const int fg = tid & 15, isl = tid >> 4;
    const int jl = tid >> 3, fb = (tid & 7) * 16;

    float acc[IPT][8] = {};
    float lsum[IPT] = {};

    __syncthreads();   // f1l/ml visible

    for (int j0 = 0; j0 < N; j0 += JT) {
        const float* src = hsrc + ((long)(bz * N + j0 + jl) * HH + hy) * F + fb;
        float4 v0 = *(const float4*)(src);
        float4 v1 = *(const float4*)(src + 4);
        float4 v2 = *(const float4*)(src + 8);
        float4 v3 = *(const float4*)(src + 12);

        float pk[IPT * 2];
#pragma unroll
        for (int k = 0; k < IPT * 2; ++k) {
            int v = tid + 256 * k;
            int ii = v & (ITILE - 1);
            int jj = v / ITILE;
            float e = lrelu(f1l[ii] + f2g[hb * N + j0 + jj]);
            pk[k] = __expf(e - ml[ii]);
        }

        __syncthreads();   // previous tile fully consumed
        *(float4*)&hlds[jl][fb]      = v0;
        *(float4*)&hlds[jl][fb + 4]  = v1;
        *(float4*)&hlds[jl][fb + 8]  = v2;
        *(float4*)&hlds[jl][fb + 12] = v3;
#pragma unroll
        for (int k = 0; k < IPT * 2; ++k) {
            int v = tid + 256 * k;
            plds[v / ITILE][v & (ITILE - 1)] = pk[k];
        }
        __syncthreads();

#pragma unroll
        for (int jj = 0; jj < JT; ++jj) {
            float4 hA = *(float4*)&hlds[jj][fg * 8];
            float4 hB = *(float4*)&hlds[jj][fg * 8 + 4];
#pragma unroll
            for (int r = 0; r < IPT; ++r) {
                float p = plds[jj][isl + 16 * r];
                lsum[r] += p;
                acc[r][0] += p * hA.x; acc[r][1] += p * hA.y;
                acc[r][2] += p * hA.z; acc[r][3] += p * hA.w;
                acc[r][4] += p * hB.x; acc[r][5] += p * hB.y;
                acc[r][6] += p * hB.z; acc[r][7] += p * hB.w;
            }
        }
    }

#pragma unroll
    for (int r = 0; r < IPT; ++r) {
        float inv = 1.f / lsum[r];
        int i = i0 + isl + 16 * r;
        float o[8];
#pragma unroll
        for (int c = 0; c < 8; ++c) {
            float t = acc[r][c] * inv;
            t = elu1(t);
            if (elu2) t = elu1(t);
            o[c] = t;
        }
        float* dst = out + ((long)(bz * N + i) * HH + hy) * F + fg * 8;
        *(float4*)(dst)     = make_float4(o[0], o[1], o[2], o[3]);
        *(float4*)(dst + 4) = make_float4(o[4], o[5], o[6], o[7]);
    }
}

// ---------------------------------------------------------------------------
// B=8, N=1024, D=256, H=8, F=128
// in: x(8,1024,256), adj(unused), W_heads(8,256,128), a_heads(8,256,1),
//     W_out(1024,128), a_out(256,1)
// out: (8,1024,128) f32
// ---------------------------------------------------------------------------
extern "C" void kernel_launch(void* const* d_in, const int* in_sizes, int n_in,
                              void* d_out, int out_size, void* d_ws, size_t ws_size,
                              hipStream_t stream)
{
    const float* x  = (const float*)d_in[0];
    const float* Wh = (const float*)d_in[2];
    const float* ah = (const float*)d_in[3];
    const float* Wo = (const float*)d_in[4];
    const float* ao = (const float*)d_in[5];
    float* out = (float*)d_out;

    float* ws = (float*)d_ws;
    float* h1   = ws;                 // [8192][1024] = h1[b][n][h][f]
    float* xc   = h1 + 8388608;       // [8192][1024] = elu(h') concat-heads
    float* h2   = xc + 8388608;       // [8192][128]
    float* f1a  = h2 + 1048576;       // [8][8192]
    float* f2a  = f1a + 65536;        // [8][8192]
    float* f2ma = f2a + 65536;        // [64]
    float* f1b  = f2ma + 64;          // [8192]
    float* f2b  = f1b + 8192;         // [8192]
    float* f2mb = f2b + 8192;         // [8]

    // Layer 1: h1[b][n][h][f] = x[b][n][:] @ W_heads[h][:][f]
    gemm64<<<dim3(2, 128, 8), 256, 0, stream>>>(x, Wh, h1, 256, 256, 128, 1024,
                                                (long)256 * 128, 128);
    fdot<<<16384, 256, 0, stream>>>(h1, ah, f1a, f2a, 8, 8192);
    colmax<<<64, 64, 0, stream>>>(f2a, f2ma, 1024);
    attn<4><<<dim3(16, 8, 8), 256, 0, stream>>>(h1, f1a, f2a, f2ma, xc, 1024, 8, 0);

    // Layer 2: h2 = xc @ W_out
    gemm64<<<dim3(2, 128, 1), 256, 0, stream>>>(xc, Wo, h2, 1024, 1024, 128, 128,
                                                0L, 0);
    fdot<<<2048, 256, 0, stream>>>(h2, ao, f1b, f2b, 1, 8192);
    colmax<<<8, 64, 0, stream>>>(f2b, f2mb, 1024);
    attn<1><<<dim3(64, 1, 8), 256, 0, stream>>>(h2, f1b, f2b, f2mb, out, 1024, 1, 1);
}

// Round 3
// 338.479 us; speedup vs baseline: 1.7959x; 1.7959x over previous
//
#include <hip/hip_runtime.h>
#include <math.h>

#define ALPHA 0.2f

typedef __attribute__((ext_vector_type(8))) short bf16x8;
typedef __attribute__((ext_vector_type(4))) float f32x4;

__device__ __forceinline__ float lrelu(float x) { return x > 0.f ? x : ALPHA * x; }
__device__ __forceinline__ float elu1(float x)  { return x > 0.f ? x : (__expf(x) - 1.f); }

// round-to-nearest-even f32 -> bf16 (values are finite; no NaN handling needed)
__device__ __forceinline__ unsigned short f2bf(float x) {
    unsigned u = __float_as_uint(x);
    return (unsigned short)((u + 0x7fffu + ((u >> 16) & 1u)) >> 16);
}
__device__ __forceinline__ unsigned pkbf16(float a, float b) {
    return (unsigned)f2bf(a) | ((unsigned)f2bf(b) << 16);
}

// ---------------------------------------------------------------------------
// Generic f32 GEMM: C[m][j] (+z col offset) = sum_k A[m][k] * B_z[k][j]
// tile 64x64, Ktile 16, 256 threads, 4x4 micro-tile per thread.
// grid: (Ncols/64, M/64, Z)
// ---------------------------------------------------------------------------
__global__ __launch_bounds__(256) void gemm64(
    const float* __restrict__ A, const float* __restrict__ B, float* __restrict__ C,
    int K, int lda, int ldb, int ldc, long bzStride, int czColOff)
{
    __shared__ float As[64][20];
    __shared__ float Bs[16][64];

    const int tid = threadIdx.x;
    const int tx = tid & 15, ty = tid >> 4;
    const int m0 = blockIdx.y * 64;
    const int j0 = blockIdx.x * 64;
    const int z  = blockIdx.z;

    const float* Bz = B + (long)z * bzStride;
    float*       Cz = C + (long)z * czColOff;

    const int ar = tid >> 2,  ac = (tid & 3) * 4;
    const int br = tid >> 4,  bc = (tid & 15) * 4;

    float acc[4][4] = {};

    for (int k0 = 0; k0 < K; k0 += 16) {
        float4 av = *(const float4*)(A  + (long)(m0 + ar) * lda + k0 + ac);
        float4 bv = *(const float4*)(Bz + (long)(k0 + br) * ldb + j0 + bc);
        __syncthreads();
        *(float4*)&As[ar][ac] = av;
        *(float4*)&Bs[br][bc] = bv;
        __syncthreads();
#pragma unroll
        for (int kk = 0; kk < 16; ++kk) {
            float a0 = As[ty * 4 + 0][kk];
            float a1 = As[ty * 4 + 1][kk];
            float a2 = As[ty * 4 + 2][kk];
            float a3 = As[ty * 4 + 3][kk];
            float4 b = *(float4*)&Bs[kk][tx * 4];
            acc[0][0] += a0 * b.x; acc[0][1] += a0 * b.y; acc[0][2] += a0 * b.z; acc[0][3] += a0 * b.w;
            acc[1][0] += a1 * b.x; acc[1][1] += a1 * b.y; acc[1][2] += a1 * b.z; acc[1][3] += a1 * b.w;
            acc[2][0] += a2 * b.x; acc[2][1] += a2 * b.y; acc[2][2] += a2 * b.z; acc[2][3] += a2 * b.w;
            acc[3][0] += a3 * b.x; acc[3][1] += a3 * b.y; acc[3][2] += a3 * b.z; acc[3][3] += a3 * b.w;
        }
    }
#pragma unroll
    for (int r = 0; r < 4; ++r) {
        float4 o = make_float4(acc[r][0], acc[r][1], acc[r][2], acc[r][3]);
        *(float4*)(Cz + (long)(m0 + ty * 4 + r) * ldc + j0 + tx * 4) = o;
    }
}

// ---------------------------------------------------------------------------
// f1/f2: one wave per (h, row). hsrc layout [row][HH][128]; a layout [h][256].
// ---------------------------------------------------------------------------
__global__ __launch_bounds__(256) void fdot(
    const float* __restrict__ hsrc, const float* __restrict__ a,
    float* __restrict__ f1, float* __restrict__ f2, int HH, int BN)
{
    const int w = blockIdx.x * 4 + (threadIdx.x >> 6);
    const int lane = threadIdx.x & 63;
    const int h = w / BN;
    const int rn = w - h * BN;

    const float* row = hsrc + ((long)rn * HH + h) * 128;
    const float* ah = a + h * 256;

    float2 v = *(const float2*)(row + lane * 2);
    float s1 = v.x * ah[lane * 2] + v.y * ah[lane * 2 + 1];
    float s2 = v.x * ah[128 + lane * 2] + v.y * ah[128 + lane * 2 + 1];
#pragma unroll
    for (int off = 32; off; off >>= 1) {
        s1 += __shfl_down(s1, off);
        s2 += __shfl_down(s2, off);
    }
    if (lane == 0) {
        f1[h * BN + rn] = s1;
        f2[h * BN + rn] = s2;
    }
}

__global__ __launch_bounds__(64) void colmax(
    const float* __restrict__ f2, float* __restrict__ f2max, int N)
{
    const int hb = blockIdx.x;
    const int lane = threadIdx.x;
    float m = -1e30f;
    for (int k = lane; k < N; k += 64) m = fmaxf(m, f2[hb * N + k]);
#pragma unroll
    for (int off = 32; off; off >>= 1) m = fmaxf(m, __shfl_down(m, off));
    if (lane == 0) f2max[hb] = m;
}

// ---------------------------------------------------------------------------
// MFMA attention: out[b][i][h][f] = act( (1/l_i) * sum_j p_ij * hsrc[b][j][h][f] )
// p_ij = exp(lrelu(f1_i+f2_j) - m_i), m_i = lrelu(f1_i + max_j f2_j) (exact).
// 16x16x32 bf16 MFMA. P built directly in A-operand layout in registers
// (lane: i = lane&15 (+16*ii), k = quad*8+j). h-tile staged TRANSPOSED in
// LDS as bf16 (hT[f][j], padded row 72) so B-frags are contiguous ds_read_b128.
// Block = 4 waves; wave w owns 16*NI i-rows x 128 f (NI x 8 C-tiles).
// grid: (N/(64*NI), H, B)
// ---------------------------------------------------------------------------
template <int NI>
__global__ __launch_bounds__(256) void attn_mfma(
    const float* __restrict__ hsrc, const float* __restrict__ f1g,
    const float* __restrict__ f2g, const float* __restrict__ f2maxg,
    float* __restrict__ out, int N, int HH, int elu2)
{
    const int JT = 64, JP = JT + 8;   // padded hT row: 72 bf16 = 144 B (9x16B)
    __shared__ __align__(16) unsigned short hT[128][JP];
    __shared__ float lsums[64 * NI];

    const int tid = threadIdx.x;
    const int w = tid >> 6, lane = tid & 63;
    const int n16 = lane & 15, quad = lane >> 4;
    const int hy = blockIdx.y, bz = blockIdx.z;
    const int hb = hy * gridDim.z + bz;          // h*B + b
    const int ITILE = 64 * NI;
    const int iw0 = blockIdx.x * ITILE + w * (16 * NI);

    float f1r[NI], mr[NI], lsum[NI];
    const float f2m = f2maxg[hb];
#pragma unroll
    for (int ii = 0; ii < NI; ++ii) {
        float v = f1g[(long)hb * N + iw0 + ii * 16 + n16];
        f1r[ii] = v;
        mr[ii] = lrelu(v + f2m);
        lsum[ii] = 0.f;
    }

    f32x4 acc[NI][8];
#pragma unroll
    for (int ii = 0; ii < NI; ++ii)
#pragma unroll
        for (int t = 0; t < 8; ++t) acc[ii][t] = (f32x4){0.f, 0.f, 0.f, 0.f};

    const float* f2row = f2g + (long)hb * N;

    for (int j0 = 0; j0 < N; j0 += JT) {
        // --- stage h-tile: global f32 [j][f] -> LDS bf16 hT[f][j] (transposed)
        float4 ga[4][2];
#pragma unroll
        for (int tt = 0; tt < 4; ++tt) {
            int v = tid + 256 * tt;
            int f4 = v & 31, jp = v >> 5;               // f-group of 4, j-pair
            const float* s0 = hsrc + ((long)(bz * N + j0 + jp * 2) * HH + hy) * 128 + f4 * 4;
            ga[tt][0] = *(const float4*)s0;
            ga[tt][1] = *(const float4*)(s0 + (long)HH * 128);
        }
        __syncthreads();   // previous tile fully consumed
#pragma unroll
        for (int tt = 0; tt < 4; ++tt) {
            int v = tid + 256 * tt;
            int f4 = v & 31, jp = v >> 5;
            const float* p0 = (const float*)&ga[tt][0];
            const float* p1 = (const float*)&ga[tt][1];
#pragma unroll
            for (int c = 0; c < 4; ++c)
                *(unsigned*)&hT[f4 * 4 + c][jp * 2] = pkbf16(p0[c], p1[c]);
        }
        __syncthreads();   // hT ready

        // --- compute: 2 k-steps of 32 j
#pragma unroll
        for (int kk = 0; kk < 2; ++kk) {
            const int jb = j0 + kk * 32 + quad * 8;
            float4 f2a = *(const float4*)(f2row + jb);
            float4 f2b = *(const float4*)(f2row + jb + 4);
            float f2v[8] = {f2a.x, f2a.y, f2a.z, f2a.w, f2b.x, f2b.y, f2b.z, f2b.w};

            bf16x8 afr[NI];
#pragma unroll
            for (int ii = 0; ii < NI; ++ii) {
                float p[8];
#pragma unroll
                for (int jj = 0; jj < 8; ++jj) {
                    float e = lrelu(f1r[ii] + f2v[jj]);
                    p[jj] = __expf(e - mr[ii]);
                    lsum[ii] += p[jj];
                }
                union { bf16x8 v; unsigned u[4]; } cvt;
#pragma unroll
                for (int q = 0; q < 4; ++q) cvt.u[q] = pkbf16(p[2 * q], p[2 * q + 1]);
                afr[ii] = cvt.v;
            }
#pragma unroll
            for (int t = 0; t < 8; ++t) {
                bf16x8 bfr = *(const bf16x8*)&hT[t * 16 + n16][kk * 32 + quad * 8];
#pragma unroll
                for (int ii = 0; ii < NI; ++ii)
                    acc[ii][t] = __builtin_amdgcn_mfma_f32_16x16x32_bf16(
                        afr[ii], bfr, acc[ii][t], 0, 0, 0);
            }
        }
    }

    // --- reduce lsum across quads (lanes n, n+16, n+32, n+48 cover all j)
#pragma unroll
    for (int ii = 0; ii < NI; ++ii) {
        float v = lsum[ii];
        v += __shfl_xor(v, 16);
        v += __shfl_xor(v, 32);
        if (lane < 16) lsums[w * 16 * NI + ii * 16 + lane] = v;
    }
    __syncthreads();

    // --- epilogue: C/D layout col=lane&15, row=quad*4+reg
#pragma unroll
    for (int ii = 0; ii < NI; ++ii) {
#pragma unroll
        for (int r = 0; r < 4; ++r) {
            int il = w * 16 * NI + ii * 16 + quad * 4 + r;
            float inv = 1.f / lsums[il];
            int i = blockIdx.x * ITILE + il;
            float* dst = out + ((long)(bz * N + i) * HH + hy) * 128 + n16;
#pragma unroll
            for (int t = 0; t < 8; ++t) {
                float tv = acc[ii][t][r] * inv;
                tv = elu1(tv);
                if (elu2) tv = elu1(tv);
                dst[t * 16] = tv;
            }
        }
    }
}

// ---------------------------------------------------------------------------
// B=8, N=1024, D=256, H=8, F=128
// ---------------------------------------------------------------------------
extern "C" void kernel_launch(void* const* d_in, const int* in_sizes, int n_in,
                              void* d_out, int out_size, void* d_ws, size_t ws_size,
                              hipStream_t stream)
{
    const float* x  = (const float*)d_in[0];
    const float* Wh = (const float*)d_in[2];
    const float* ah = (const float*)d_in[3];
    const float* Wo = (const float*)d_in[4];
    const float* ao = (const float*)d_in[5];
    float* out = (float*)d_out;

    float* ws = (float*)d_ws;
    float* h1   = ws;                 // [8192][1024] = h1[b][n][h][f]
    float* xc   = h1 + 8388608;       // [8192][1024]
    float* h2   = xc + 8388608;       // [8192][128]
    float* f1a  = h2 + 1048576;       // [8][8192]
    float* f2a  = f1a + 65536;        // [8][8192]
    float* f2ma = f2a + 65536;        // [64]
    float* f1b  = f2ma + 64;          // [8192]
    float* f2b  = f1b + 8192;        // [8192]
    float* f2mb = f2b + 8192;        // [8]

    // Layer 1
    gemm64<<<dim3(2, 128, 8), 256, 0, stream>>>(x, Wh, h1, 256, 256, 128, 1024,
                                                (long)256 * 128, 128);
    fdot<<<16384, 256, 0, stream>>>(h1, ah, f1a, f2a, 8, 8192);
    colmax<<<64, 64, 0, stream>>>(f2a, f2ma, 1024);
    attn_mfma<2><<<dim3(8, 8, 8), 256, 0, stream>>>(h1, f1a, f2a, f2ma, xc, 1024, 8, 0);

    // Layer 2
    gemm64<<<dim3(2, 128, 1), 256, 0, stream>>>(xc, Wo, h2, 1024, 1024, 128, 128,
                                                0L, 0);
    fdot<<<2048, 256, 0, stream>>>(h2, ao, f1b, f2b, 1, 8192);
    colmax<<<8, 64, 0, stream>>>(f2b, f2mb, 1024);
    attn_mfma<1><<<dim3(16, 1, 8), 256, 0, stream>>>(h2, f1b, f2b, f2mb, out, 1024, 1, 1);
}

// Round 4
// 261.741 us; speedup vs baseline: 2.3225x; 1.2932x over previous
//
#include <hip/hip_runtime.h>
#include <math.h>

#define ALPHA 0.2f
#define LOG2E 1.44269504089f

typedef __attribute__((ext_vector_type(8))) short bf16x8;
typedef __attribute__((ext_vector_type(4))) float f32x4;

__device__ __forceinline__ float lrelu(float x) { return fmaxf(x, ALPHA * x); }
__device__ __forceinline__ float elu1(float x)  { return x > 0.f ? x : (__expf(x) - 1.f); }

// round-to-nearest-even f32 -> bf16 (finite values only)
__device__ __forceinline__ unsigned short f2bf(float x) {
    unsigned u = __float_as_uint(x);
    return (unsigned short)((u + 0x7fffu + ((u >> 16) & 1u)) >> 16);
}
__device__ __forceinline__ unsigned pkbf16(float a, float b) {
    return (unsigned)f2bf(a) | ((unsigned)f2bf(b) << 16);
}
__device__ __forceinline__ float bflo(unsigned v) { return __uint_as_float(v << 16); }
__device__ __forceinline__ float bfhi(unsigned v) { return __uint_as_float(v & 0xffff0000u); }

// ---------------------------------------------------------------------------
// Prep: x f32 -> bf16 (contiguous)
// ---------------------------------------------------------------------------
__global__ __launch_bounds__(256) void cvt_x(
    const float* __restrict__ x, unsigned short* __restrict__ xb)
{
    int idx = (blockIdx.x * 256 + threadIdx.x) * 4;
    float4 v = *(const float4*)(x + idx);
    uint2 o = make_uint2(pkbf16(v.x, v.y), pkbf16(v.z, v.w));
    *(uint2*)(xb + idx) = o;
}

// ---------------------------------------------------------------------------
// Prep: W [z][K][128] f32 -> WT [z][128][K] bf16 (k-contiguous rows = B-frag)
// grid (128, Z), block 256: block = (n, z), thread loops k.
// ---------------------------------------------------------------------------
__global__ __launch_bounds__(256) void cvt_wT(
    const float* __restrict__ Win, unsigned short* __restrict__ Wout, int K)
{
    const int n = blockIdx.x, z = blockIdx.y;
    const float* in = Win + (size_t)z * K * 128;
    unsigned short* out = Wout + (size_t)z * 128 * K + (size_t)n * K;
    for (int k = threadIdx.x; k < K; k += 256)
        out[k] = f2bf(in[(size_t)k * 128 + n]);
}

// ---------------------------------------------------------------------------
// bf16 MFMA GEMM, LDS-free (L2-resident operands), transposed C store.
// A[m][k] bf16 (lda=K), Bt[z][n][k] bf16, Ct[z][n][m=8192] bf16.
// Block 256 = 4 waves (2x2 over 128m x 128n); wave tile 64m x 64n.
// grid (M/128, 1, Z). 16x16x32 MFMA, K-step 32.
// ---------------------------------------------------------------------------
__global__ __launch_bounds__(256) void gemm_mfma(
    const unsigned short* __restrict__ A, const unsigned short* __restrict__ Bt,
    unsigned short* __restrict__ Ct, int K)
{
    const int tid = threadIdx.x;
    const int w = tid >> 6, lane = tid & 63;
    const int n16 = lane & 15, quad = lane >> 4;
    const int wm = (w & 1) * 64, wn = (w >> 1) * 64;
    const int m_base = blockIdx.x * 128 + wm;
    const int z = blockIdx.z;

    const unsigned short* Bz = Bt + (size_t)z * 128 * K;
    unsigned short* Ctz = Ct + (size_t)z * 128 * 8192;

    f32x4 acc[4][4];
#pragma unroll
    for (int mm = 0; mm < 4; ++mm)
#pragma unroll
        for (int nn = 0; nn < 4; ++nn) acc[mm][nn] = (f32x4){0.f, 0.f, 0.f, 0.f};

#pragma unroll 2
    for (int k0 = 0; k0 < K; k0 += 32) {
        bf16x8 am[4], bn[4];
#pragma unroll
        for (int mm = 0; mm < 4; ++mm)
            am[mm] = *(const bf16x8*)(A + (size_t)(m_base + mm * 16 + n16) * K + k0 + quad * 8);
#pragma unroll
        for (int nn = 0; nn < 4; ++nn)
            bn[nn] = *(const bf16x8*)(Bz + (size_t)(wn + nn * 16 + n16) * K + k0 + quad * 8);
#pragma unroll
        for (int mm = 0; mm < 4; ++mm)
#pragma unroll
            for (int nn = 0; nn < 4; ++nn)
                acc[mm][nn] = __builtin_amdgcn_mfma_f32_16x16x32_bf16(
                    am[mm], bn[nn], acc[mm][nn], 0, 0, 0);
    }

    // C^T store: Ct[n][m], lane col n16 -> n row, 4 consecutive m per reg quad.
#pragma unroll
    for (int nn = 0; nn < 4; ++nn) {
        int n = wn + nn * 16 + n16;
#pragma unroll
        for (int mm = 0; mm < 4; ++mm) {
            int mrow = m_base + mm * 16 + quad * 4;
            f32x4 a = acc[mm][nn];
            ushort4 o = make_ushort4(f2bf(a[0]), f2bf(a[1]), f2bf(a[2]), f2bf(a[3]));
            *(ushort4*)(Ctz + (size_t)n * 8192 + mrow) = o;
        }
    }
}

// ---------------------------------------------------------------------------
// f1/f2 + per-(z,b) f2max, from transposed bf16 hT[z][f][8192].
// grid (B=8, Z), block 256; thread handles 4 consecutive m. Coalesced.
// f1[z*8192+m] = sum_f hT[z][f][m]*a[z][f]; f2 with a[z][128+f].
// ---------------------------------------------------------------------------
__global__ __launch_bounds__(256) void fdot_max(
    const unsigned short* __restrict__ hT, const float* __restrict__ a,
    float* __restrict__ f1, float* __restrict__ f2, float* __restrict__ f2max)
{
    __shared__ float red[256];
    const int tid = threadIdx.x;
    const int b = blockIdx.x, z = blockIdx.y;
    const int m0 = b * 1024 + tid * 4;
    const float* az = a + z * 256;

    float s1[4] = {}, s2[4] = {};
#pragma unroll 4
    for (int f = 0; f < 128; ++f) {
        uint2 v = *(const uint2*)(hT + ((size_t)(z * 128 + f)) * 8192 + m0);
        float a1 = az[f], a2 = az[128 + f];
        float h0 = bflo(v.x), h1 = bfhi(v.x), h2 = bflo(v.y), h3 = bfhi(v.y);
        s1[0] += h0 * a1; s1[1] += h1 * a1; s1[2] += h2 * a1; s1[3] += h3 * a1;
        s2[0] += h0 * a2; s2[1] += h1 * a2; s2[2] += h2 * a2; s2[3] += h3 * a2;
    }
    *(float4*)(f1 + (size_t)z * 8192 + m0) = make_float4(s1[0], s1[1], s1[2], s1[3]);
    *(float4*)(f2 + (size_t)z * 8192 + m0) = make_float4(s2[0], s2[1], s2[2], s2[3]);

    float m4 = fmaxf(fmaxf(s2[0], s2[1]), fmaxf(s2[2], s2[3]));
    red[tid] = m4;
    __syncthreads();
    for (int s = 128; s; s >>= 1) {
        if (tid < s) red[tid] = fmaxf(red[tid], red[tid + s]);
        __syncthreads();
    }
    if (tid == 0) f2max[z * gridDim.x + b] = red[0];
}

// ---------------------------------------------------------------------------
// MFMA attention, LDS-free B-frags from transposed global hT[z][f][8192].
// p_ij = exp(lrelu(f1_i+f2_j) - m_i), exact softmax (m_i analytic).
// P built in-register in A-frag layout; B-frag = 16B global load (L2/L3).
// Block 256 = 4 waves; wave owns 16*NI i-rows x 128 f.
// grid (N/(64*NI), Z, B). OUTBF: write bf16 concat layout [m][z*128+f],
// else f32 [m][128] (with optional second elu).
// ---------------------------------------------------------------------------
template <int NI, int OUTBF>
__global__ __launch_bounds__(256) void attn_mfma2(
    const unsigned short* __restrict__ hT, const float* __restrict__ f1g,
    const float* __restrict__ f2g, const float* __restrict__ f2maxg,
    float* __restrict__ outf, unsigned short* __restrict__ outb, int elu2)
{
    const int N = 1024;
    __shared__ float f2l[1024];
    __shared__ float lsums[64 * NI];

    const int tid = threadIdx.x;
    const int w = tid >> 6, lane = tid & 63;
    const int n16 = lane & 15, quad = lane >> 4;
    const int hy = blockIdx.y, bz = blockIdx.z;
    const int hb = hy * gridDim.z + bz;
    const int ITILE = 64 * NI;
    const int iw0 = blockIdx.x * ITILE + w * (16 * NI);

    // preload f2 slice to LDS (4 KB)
    ((float4*)f2l)[tid] = ((const float4*)(f2g + (size_t)hb * N))[tid];

    const float f2m = f2maxg[hb];
    float f1r[NI], mc[NI], lsum[NI];
#pragma unroll
    for (int ii = 0; ii < NI; ++ii) {
        float v = f1g[(size_t)hb * N + iw0 + ii * 16 + n16];
        f1r[ii] = v;
        mc[ii] = lrelu(v + f2m) * LOG2E;
        lsum[ii] = 0.f;
    }

    f32x4 acc[NI][8];
#pragma unroll
    for (int ii = 0; ii < NI; ++ii)
#pragma unroll
        for (int t = 0; t < 8; ++t) acc[ii][t] = (f32x4){0.f, 0.f, 0.f, 0.f};

    // B-frag base: hT[(hy*128 + f)][bz*1024 + j]
    const unsigned short* hb0 = hT + (size_t)hy * 128 * 8192 + bz * 1024 + quad * 8;

    __syncthreads();   // f2l ready

#pragma unroll 2
    for (int j0 = 0; j0 < N; j0 += 32) {
        // issue B-frag loads early (L2-resident)
        bf16x8 bfr[8];
#pragma unroll
        for (int t = 0; t < 8; ++t)
            bfr[t] = *(const bf16x8*)(hb0 + (size_t)(t * 16 + n16) * 8192 + j0);

        // p in A-frag layout: i = lane&15 (+16*ii), k = quad*8 + jj
        float4 f2a = *(const float4*)(f2l + j0 + quad * 8);
        float4 f2b = *(const float4*)(f2l + j0 + quad * 8 + 4);
        float f2v[8] = {f2a.x, f2a.y, f2a.z, f2a.w, f2b.x, f2b.y, f2b.z, f2b.w};

        bf16x8 afr[NI];
#pragma unroll
        for (int ii = 0; ii < NI; ++ii) {
            float p[8];
#pragma unroll
            for (int jj = 0; jj < 8; ++jj) {
                float e = lrelu(f1r[ii] + f2v[jj]);
                p[jj] = __builtin_amdgcn_exp2f(fmaf(e, LOG2E, -mc[ii]));
                lsum[ii] += p[jj];
            }
            union { bf16x8 v; unsigned u[4]; } cvt;
#pragma unroll
            for (int q = 0; q < 4; ++q) cvt.u[q] = pkbf16(p[2 * q], p[2 * q + 1]);
            afr[ii] = cvt.v;
        }
#pragma unroll
        for (int t = 0; t < 8; ++t)
#pragma unroll
            for (int ii = 0; ii < NI; ++ii)
                acc[ii][t] = __builtin_amdgcn_mfma_f32_16x16x32_bf16(
                    afr[ii], bfr[t], acc[ii][t], 0, 0, 0);
    }

    // reduce lsum across quads (lanes n, n+16, n+32, n+48 cover all j)
#pragma unroll
    for (int ii = 0; ii < NI; ++ii) {
        float v = lsum[ii];
        v += __shfl_xor(v, 16);
        v += __shfl_xor(v, 32);
        if (lane < 16) lsums[w * 16 * NI + ii * 16 + lane] = v;
    }
    __syncthreads();

    // epilogue: C/D layout col=lane&15 (f), row=quad*4+reg (i)
#pragma unroll
    for (int ii = 0; ii < NI; ++ii) {
#pragma unroll
        for (int r = 0; r < 4; ++r) {
            int il = w * 16 * NI + ii * 16 + quad * 4 + r;
            float inv = 1.f / lsums[il];
            int i = blockIdx.x * ITILE + il;
#pragma unroll
            for (int t = 0; t < 8; ++t) {
                float tv = acc[ii][t][r] * inv;
                tv = elu1(tv);
                if (OUTBF) {
                    outb[(size_t)(bz * 1024 + i) * 1024 + hy * 128 + t * 16 + n16] = f2bf(tv);
                } else {
                    if (elu2) tv = elu1(tv);
                    outf[(size_t)(bz * 1024 + i) * 128 + t * 16 + n16] = tv;
                }
            }
        }
    }
}

// ---------------------------------------------------------------------------
// B=8, N=1024, D=256, H=8, F=128
// ---------------------------------------------------------------------------
extern "C" void kernel_launch(void* const* d_in, const int* in_sizes, int n_in,
                              void* d_out, int out_size, void* d_ws, size_t ws_size,
                              hipStream_t stream)
{
    const float* x  = (const float*)d_in[0];
    const float* Wh = (const float*)d_in[2];
    const float* ah = (const float*)d_in[3];
    const float* Wo = (const float*)d_in[4];
    const float* ao = (const float*)d_in[5];
    float* out = (float*)d_out;

    unsigned short* xb  = (unsigned short*)d_ws;       // [8192][256]   4 MB
    unsigned short* WhT = xb + 2097152;                // [8][128][256] 512 KB
    unsigned short* WoT = WhT + 262144;                // [128][1024]   256 KB
    unsigned short* h1T = WoT + 131072;                // [8][128][8192] 16 MB
    unsigned short* xcb = h1T + 8388608;               // [8192][1024]  16 MB
    unsigned short* h2T = xcb + 8388608;               // [128][8192]   2 MB
    float* f1a  = (float*)(h2T + 1048576);             // [8][8192]
    float* f2a  = f1a + 65536;                         // [8][8192]
    float* f2ma = f2a + 65536;                         // [64]
    float* f1b  = f2ma + 64;                           // [8192]
    float* f2b  = f1b + 8192;                          // [8192]
    float* f2mb = f2b + 8192;                          // [8]

    // prep
    cvt_x<<<2048, 256, 0, stream>>>(x, xb);
    cvt_wT<<<dim3(128, 8), 256, 0, stream>>>(Wh, WhT, 256);
    cvt_wT<<<dim3(128, 1), 256, 0, stream>>>(Wo, WoT, 1024);

    // Layer 1: h1T[h][f][m] = (x @ Wh[h])^T
    gemm_mfma<<<dim3(64, 1, 8), 256, 0, stream>>>(xb, WhT, h1T, 256);
    fdot_max<<<dim3(8, 8), 256, 0, stream>>>(h1T, ah, f1a, f2a, f2ma);
    attn_mfma2<2, 1><<<dim3(8, 8, 8), 256, 0, stream>>>(h1T, f1a, f2a, f2ma,
                                                        nullptr, xcb, 0);

    // Layer 2: h2T[f][m] = (xc @ Wo)^T
    gemm_mfma<<<dim3(64, 1, 1), 256, 0, stream>>>(xcb, WoT, h2T, 1024);
    fdot_max<<<dim3(8, 1), 256, 0, stream>>>(h2T, ao, f1b, f2b, f2mb);
    attn_mfma2<1, 0><<<dim3(16, 1, 8), 256, 0, stream>>>(h2T, f1b, f2b, f2mb,
                                                         out, nullptr, 1);
}

// Round 5
// 196.991 us; speedup vs baseline: 3.0858x; 1.3287x over previous
//
#include <hip/hip_runtime.h>
#include <math.h>

#define ALPHA 0.2f
#define LOG2E 1.44269504089f

typedef __attribute__((ext_vector_type(8))) short bf16x8;
typedef __attribute__((ext_vector_type(4))) float f32x4;

__device__ __forceinline__ float elu1(float x)  { return x > 0.f ? x : (__expf(x) - 1.f); }

// round-to-nearest-even f32 -> bf16 (finite values only)
__device__ __forceinline__ unsigned short f2bf(float x) {
    unsigned u = __float_as_uint(x);
    return (unsigned short)((u + 0x7fffu + ((u >> 16) & 1u)) >> 16);
}
__device__ __forceinline__ unsigned pkbf16(float a, float b) {
    return (unsigned)f2bf(a) | ((unsigned)f2bf(b) << 16);
}
__device__ __forceinline__ float bflo(unsigned v) { return __uint_as_float(v << 16); }
__device__ __forceinline__ float bfhi(unsigned v) { return __uint_as_float(v & 0xffff0000u); }

// ---------------------------------------------------------------------------
// Prep: x f32 -> bf16 (contiguous)
// ---------------------------------------------------------------------------
__global__ __launch_bounds__(256) void cvt_x(
    const float* __restrict__ x, unsigned short* __restrict__ xb)
{
    int idx = (blockIdx.x * 256 + threadIdx.x) * 4;
    float4 v = *(const float4*)(x + idx);
    uint2 o = make_uint2(pkbf16(v.x, v.y), pkbf16(v.z, v.w));
    *(uint2*)(xb + idx) = o;
}

// ---------------------------------------------------------------------------
// Prep: W [z][K][128] f32 -> WT [z][128][K] bf16 via LDS 64x64 tile transpose.
// Coalesced global reads and writes. grid (K/64, 2, Z), block 256.
// ---------------------------------------------------------------------------
__global__ __launch_bounds__(256) void cvt_wT_lds(
    const float* __restrict__ Win, unsigned short* __restrict__ Wout, int K)
{
    __shared__ float T[64][65];
    const int tid = threadIdx.x;
    const int k0 = blockIdx.x * 64, n0 = blockIdx.y * 64, z = blockIdx.z;
    const float* in = Win + (size_t)z * K * 128;
    unsigned short* out = Wout + (size_t)z * 128 * K;

    const int kr = tid >> 4, nc = (tid & 15) * 4;
#pragma unroll
    for (int s = 0; s < 4; ++s) {
        float4 v = *(const float4*)(in + (size_t)(k0 + kr + s * 16) * 128 + n0 + nc);
        T[kr + s * 16][nc]     = v.x;
        T[kr + s * 16][nc + 1] = v.y;
        T[kr + s * 16][nc + 2] = v.z;
        T[kr + s * 16][nc + 3] = v.w;
    }
    __syncthreads();
    const int nr0 = tid >> 3, kc = (tid & 7) * 8;
#pragma unroll
    for (int s = 0; s < 2; ++s) {
        int nr = nr0 + s * 32;
        unsigned pk[4];
#pragma unroll
        for (int q = 0; q < 4; ++q)
            pk[q] = pkbf16(T[kc + 2 * q][nr], T[kc + 2 * q + 1][nr]);
        *(uint4*)(out + (size_t)(n0 + nr) * K + k0 + kc) = make_uint4(pk[0], pk[1], pk[2], pk[3]);
    }
}

// ---------------------------------------------------------------------------
// bf16 MFMA GEMM, LDS-free (L2-resident operands), transposed C store.
// A[m][k] bf16 (lda=K), Bt[z][n][k] bf16, Ct[z][n][m=8192] bf16.
// Block 256 = 4 waves (2x2 over 128m x 128n); wave tile 64m x 64n.
// grid (M/128, 1, Z). 16x16x32 MFMA, K-step 32.
// ---------------------------------------------------------------------------
__global__ __launch_bounds__(256) void gemm_mfma(
    const unsigned short* __restrict__ A, const unsigned short* __restrict__ Bt,
    unsigned short* __restrict__ Ct, int K)
{
    const int tid = threadIdx.x;
    const int w = tid >> 6, lane = tid & 63;
    const int n16 = lane & 15, quad = lane >> 4;
    const int wm = (w & 1) * 64, wn = (w >> 1) * 64;
    const int m_base = blockIdx.x * 128 + wm;
    const int z = blockIdx.z;

    const unsigned short* Bz = Bt + (size_t)z * 128 * K;
    unsigned short* Ctz = Ct + (size_t)z * 128 * 8192;

    f32x4 acc[4][4];
#pragma unroll
    for (int mm = 0; mm < 4; ++mm)
#pragma unroll
        for (int nn = 0; nn < 4; ++nn) acc[mm][nn] = (f32x4){0.f, 0.f, 0.f, 0.f};

#pragma unroll 2
    for (int k0 = 0; k0 < K; k0 += 32) {
        bf16x8 am[4], bn[4];
#pragma unroll
        for (int mm = 0; mm < 4; ++mm)
            am[mm] = *(const bf16x8*)(A + (size_t)(m_base + mm * 16 + n16) * K + k0 + quad * 8);
#pragma unroll
        for (int nn = 0; nn < 4; ++nn)
            bn[nn] = *(const bf16x8*)(Bz + (size_t)(wn + nn * 16 + n16) * K + k0 + quad * 8);
#pragma unroll
        for (int mm = 0; mm < 4; ++mm)
#pragma unroll
            for (int nn = 0; nn < 4; ++nn)
                acc[mm][nn] = __builtin_amdgcn_mfma_f32_16x16x32_bf16(
                    am[mm], bn[nn], acc[mm][nn], 0, 0, 0);
    }

    // C^T store: Ct[n][m], lane col n16 -> n row, 4 consecutive m per reg quad.
#pragma unroll
    for (int nn = 0; nn < 4; ++nn) {
        int n = wn + nn * 16 + n16;
#pragma unroll
        for (int mm = 0; mm < 4; ++mm) {
            int mrow = m_base + mm * 16 + quad * 4;
            f32x4 a = acc[mm][nn];
            ushort4 o = make_ushort4(f2bf(a[0]), f2bf(a[1]), f2bf(a[2]), f2bf(a[3]));
            *(ushort4*)(Ctz + (size_t)n * 8192 + mrow) = o;
        }
    }
}

// ---------------------------------------------------------------------------
// f1/f2 from transposed bf16 hT[z][f][8192]. grid (16, Z), block 256;
// thread = 2 consecutive m (one dword). Coalesced; a[] reads are wave-uniform.
// ---------------------------------------------------------------------------
__global__ __launch_bounds__(256) void fdot2(
    const unsigned short* __restrict__ hT, const float* __restrict__ a,
    float* __restrict__ f1, float* __restrict__ f2)
{
    const int tid = threadIdx.x;
    const int z = blockIdx.y;
    const int m0 = blockIdx.x * 512 + tid * 2;
    const float* az = a + z * 256;

    float s10 = 0.f, s11 = 0.f, s20 = 0.f, s21 = 0.f;
#pragma unroll 8
    for (int f = 0; f < 128; ++f) {
        unsigned u = *(const unsigned*)(hT + ((size_t)(z * 128 + f) << 13) + m0);
        float a1 = az[f], a2 = az[128 + f];
        float h0 = bflo(u), h1 = bfhi(u);
        s10 += h0 * a1; s11 += h1 * a1;
        s20 += h0 * a2; s21 += h1 * a2;
    }
    *(float2*)(f1 + ((size_t)z << 13) + m0) = make_float2(s10, s11);
    *(float2*)(f2 + ((size_t)z << 13) + m0) = make_float2(s20, s21);
}

// ---------------------------------------------------------------------------
// MFMA attention v3: LDS-staged B-tiles shared by all 4 waves, software-
// pipelined prefetch. p built in-register in A-frag layout; exact softmax
// (m_i analytic from in-kernel f2max). All softmax math in log2 domain
// (f2 pre-scaled by LOG2E in LDS).
// Block 256 = 4 waves; wave owns 16*NI i-rows x 128 f. grid (N/(64*NI), H, B).
// LDS tile hls[128][72]: both ds_write_b128 and ds_read_b128 patterns are
// exactly 2-way bank-aliased = free (m136).
// ---------------------------------------------------------------------------
template <int NI, int OUTBF>
__global__ __launch_bounds__(256) void attn3(
    const unsigned short* __restrict__ hT, const float* __restrict__ f1g,
    const float* __restrict__ f2g, float* __restrict__ outf,
    unsigned short* __restrict__ outb, int elu2)
{
    const int N = 1024, JT = 64, JP = 72;
    __shared__ __align__(16) unsigned short hls[128][JP];
    __shared__ float f2l[1024];
    __shared__ float wred[4];
    __shared__ float lsums[64 * NI];

    const int tid = threadIdx.x;
    const int w = tid >> 6, lane = tid & 63;
    const int n16 = lane & 15, quad = lane >> 4;
    const int hy = blockIdx.y, bz = blockIdx.z;
    const int hb = hy * gridDim.z + bz;
    const int ITILE = 64 * NI;
    const int iw0 = blockIdx.x * ITILE + w * (16 * NI);

    // f2 preload (scaled by LOG2E) + block max
    float4 fv = ((const float4*)(f2g + (size_t)hb * N))[tid];
    fv.x *= LOG2E; fv.y *= LOG2E; fv.z *= LOG2E; fv.w *= LOG2E;
    ((float4*)f2l)[tid] = fv;
    float m4 = fmaxf(fmaxf(fv.x, fv.y), fmaxf(fv.z, fv.w));
#pragma unroll
    for (int off = 32; off; off >>= 1) m4 = fmaxf(m4, __shfl_xor(m4, off));
    if (lane == 0) wred[w] = m4;

    float f1L[NI];
#pragma unroll
    for (int ii = 0; ii < NI; ++ii)
        f1L[ii] = f1g[(size_t)hb * N + iw0 + ii * 16 + n16] * LOG2E;

    __syncthreads();   // f2l + wred visible
    const float f2mL = fmaxf(fmaxf(wred[0], wred[1]), fmaxf(wred[2], wred[3]));
    float mcL[NI], lsum[NI];
#pragma unroll
    for (int ii = 0; ii < NI; ++ii) {
        float s = f1L[ii] + f2mL;
        mcL[ii] = fmaxf(s, ALPHA * s);   // = lrelu(f1+f2max)*LOG2E
        lsum[ii] = 0.f;
    }

    f32x4 acc[NI][8];
#pragma unroll
    for (int ii = 0; ii < NI; ++ii)
#pragma unroll
        for (int t = 0; t < 8; ++t) acc[ii][t] = (f32x4){0.f, 0.f, 0.f, 0.f};

    // staging coords: thread covers rows f = sf+32s, 8-j chunk sj
    const unsigned short* gsrc = hT + (size_t)hy * 128 * 8192 + bz * 1024;
    const int sf = tid >> 3, sj = (tid & 7) * 8;

    bf16x8 stg[4];
#pragma unroll
    for (int s = 0; s < 4; ++s)
        stg[s] = *(const bf16x8*)(gsrc + (size_t)(sf + 32 * s) * 8192 + sj);

    for (int jt = 0; jt < N / JT; ++jt) {
        __syncthreads();   // previous tile consumed
#pragma unroll
        for (int s = 0; s < 4; ++s)
            *(bf16x8*)&hls[sf + 32 * s][sj] = stg[s];
        __syncthreads();   // tile ready
        if (jt + 1 < N / JT) {
            int j0n = (jt + 1) * JT;
#pragma unroll
            for (int s = 0; s < 4; ++s)
                stg[s] = *(const bf16x8*)(gsrc + (size_t)(sf + 32 * s) * 8192 + j0n + sj);
        }
        const int j0 = jt * JT;
#pragma unroll
        for (int kk = 0; kk < 2; ++kk) {
            float4 fa = *(const float4*)(f2l + j0 + kk * 32 + quad * 8);
            float4 fb = *(const float4*)(f2l + j0 + kk * 32 + quad * 8 + 4);
            float f2v[8] = {fa.x, fa.y, fa.z, fa.w, fb.x, fb.y, fb.z, fb.w};

            bf16x8 afr[NI];
#pragma unroll
            for (int ii = 0; ii < NI; ++ii) {
                float p[8];
#pragma unroll
                for (int jj = 0; jj < 8; ++jj) {
                    float s = f1L[ii] + f2v[jj];
                    float t2 = fmaxf(s, ALPHA * s);
                    p[jj] = __builtin_amdgcn_exp2f(t2 - mcL[ii]);
                    lsum[ii] += p[jj];
                }
                union { bf16x8 v; unsigned u[4]; } cvt;
#pragma unroll
                for (int q = 0; q < 4; ++q) cvt.u[q] = pkbf16(p[2 * q], p[2 * q + 1]);
                afr[ii] = cvt.v;
            }
#pragma unroll
            for (int t = 0; t < 8; ++t) {
                bf16x8 bfr = *(const bf16x8*)&hls[t * 16 + n16][kk * 32 + quad * 8];
#pragma unroll
                for (int ii = 0; ii < NI; ++ii)
                    acc[ii][t] = __builtin_amdgcn_mfma_f32_16x16x32_bf16(
                        afr[ii], bfr, acc[ii][t], 0, 0, 0);
            }
        }
    }

    // lsum: reduce across quads, then LDS-transpose to C-layout rows
#pragma unroll
    for (int ii = 0; ii < NI; ++ii) {
        float v = lsum[ii];
        v += __shfl_xor(v, 16);
        v += __shfl_xor(v, 32);
        if (lane < 16) lsums[w * 16 * NI + ii * 16 + lane] = v;
    }
    __syncthreads();

    // epilogue: C/D layout col=lane&15 (f), row=quad*4+reg (i)
#pragma unroll
    for (int ii = 0; ii < NI; ++ii) {
#pragma unroll
        for (int r = 0; r < 4; ++r) {
            int il = w * 16 * NI + ii * 16 + quad * 4 + r;
            float inv = 1.f / lsums[il];
            int i = blockIdx.x * ITILE + il;
#pragma unroll
            for (int t = 0; t < 8; ++t) {
                float tv = acc[ii][t][r] * inv;
                tv = elu1(tv);
                if (OUTBF) {
                    outb[(size_t)(bz * 1024 + i) * 1024 + hy * 128 + t * 16 + n16] = f2bf(tv);
                } else {
                    if (elu2) tv = elu1(tv);
                    outf[(size_t)(bz * 1024 + i) * 128 + t * 16 + n16] = tv;
                }
            }
        }
    }
}

// ---------------------------------------------------------------------------
// B=8, N=1024, D=256, H=8, F=128
// ---------------------------------------------------------------------------
extern "C" void kernel_launch(void* const* d_in, const int* in_sizes, int n_in,
                              void* d_out, int out_size, void* d_ws, size_t ws_size,
                              hipStream_t stream)
{
    const float* x  = (const float*)d_in[0];
    const float* Wh = (const float*)d_in[2];
    const float* ah = (const float*)d_in[3];
    const float* Wo = (const float*)d_in[4];
    const float* ao = (const float*)d_in[5];
    float* out = (float*)d_out;

    unsigned short* xb  = (unsigned short*)d_ws;       // [8192][256]   4 MB
    unsigned short* WhT = xb + 2097152;                // [8][128][256] 512 KB
    unsigned short* WoT = WhT + 262144;                // [128][1024]   256 KB
    unsigned short* h1T = WoT + 131072;                // [8][128][8192] 16 MB
    unsigned short* xcb = h1T + 8388608;               // [8192][1024]  16 MB
    unsigned short* h2T = xcb + 8388608;               // [128][8192]   2 MB
    float* f1a  = (float*)(h2T + 1048576);             // [8][8192]
    float* f2a  = f1a + 65536;                         // [8][8192]
    float* f1b  = f2a + 65536;                         // [8192]
    float* f2b  = f1b + 8192;                          // [8192]

    // prep
    cvt_x<<<2048, 256, 0, stream>>>(x, xb);
    cvt_wT_lds<<<dim3(4, 2, 8), 256, 0, stream>>>(Wh, WhT, 256);
    cvt_wT_lds<<<dim3(16, 2, 1), 256, 0, stream>>>(Wo, WoT, 1024);

    // Layer 1: h1T[h][f][m] = (x @ Wh[h])^T
    gemm_mfma<<<dim3(64, 1, 8), 256, 0, stream>>>(xb, WhT, h1T, 256);
    fdot2<<<dim3(16, 8), 256, 0, stream>>>(h1T, ah, f1a, f2a);
    attn3<2, 1><<<dim3(8, 8, 8), 256, 0, stream>>>(h1T, f1a, f2a, nullptr, xcb, 0);

    // Layer 2: h2T[f][m] = (xc @ Wo)^T
    gemm_mfma<<<dim3(64, 1, 1), 256, 0, stream>>>(xcb, WoT, h2T, 1024);
    fdot2<<<dim3(16, 1), 256, 0, stream>>>(h2T, ao, f1b, f2b);
    attn3<1, 0><<<dim3(16, 1, 8), 256, 0, stream>>>(h2T, f1b, f2b, out, nullptr, 1);
}